// Round 12
// baseline (553.439 us; speedup 1.0000x reference)
//
#include <hip/hip_runtime.h>

#define N_NODES 100000
#define N_EDGES 1600000

typedef __attribute__((ext_vector_type(8))) short bf16x8;
typedef __attribute__((ext_vector_type(4))) float f32x4;
typedef __attribute__((ext_vector_type(2))) float f32x2;
typedef __attribute__((ext_vector_type(4))) unsigned short u16x4;

__device__ __forceinline__ float b2f(unsigned short u) {
    union { unsigned int i; float f; } v; v.i = ((unsigned int)u) << 16; return v.f;
}
__device__ __forceinline__ unsigned short f2b(float f) {
    union { float ff; unsigned int i; } v; v.ff = f;
    unsigned int x = v.i;
    x += 0x7fffu + ((x >> 16) & 1u);   // round-to-nearest-even
    return (unsigned short)(x >> 16);
}

// ---------------- graph-build geometry ----------------
#define NB1 8
#define WIN1 ((N_NODES + NB1 - 1) / NB1)             // 12500
#define CAP1 204800
#define PART_BLOCKS 782
#define PART_EPB 2048
#define SUBS 32
#define NWIN (NB1 * SUBS)                            // 256 windows
#define WIN2 ((WIN1 + SUBS - 1) / SUBS)              // 391
#define CAP2 8192
#define PART2_BLOCKS 2048

#define NQX 3200000                                  // x quads (12.8M/4)
#define NWEL 114688                                  // W^T elements

// ---------------- prep: cast x (quad), cast+transpose W, init counters ----------------
__global__ __launch_bounds__(256) void k_prep(
    const float* __restrict__ x,
    const float* __restrict__ pW, const float* __restrict__ W1,
    const float* __restrict__ W2, const float* __restrict__ W3,
    unsigned short* __restrict__ xb, unsigned short* __restrict__ Wb,
    int* __restrict__ gcur, int* __restrict__ gcur2)
{
    int i = blockIdx.x * 256 + threadIdx.x;
    if (i < NQX) {
        f32x4 v = *(const f32x4*)&x[(size_t)i * 4];
        u16x4 o;
        o[0] = f2b(v[0]); o[1] = f2b(v[1]); o[2] = f2b(v[2]); o[3] = f2b(v[3]);
        *(u16x4*)&xb[(size_t)i * 4] = o;
        return;
    }
    int j = i - NQX;
    if (j < NWEL) {
        const float* src; int K, base;
        if (j < 16384)      { src = pW; K = 128; base = 0; }
        else if (j < 32768) { src = W1; K = 128; base = 16384; }
        else if (j < 65536) { src = W2; K = 256; base = 32768; }
        else                { src = W3; K = 384; base = 65536; }
        int loc = j - base;
        int col = loc / K, k = loc - col * K;
        Wb[j] = f2b(src[(size_t)k * 128 + col]);
        return;
    }
    int k = j - NWEL;
    if (k < NB1) gcur[k] = k * CAP1;
    else if (k < NB1 + NWIN) gcur2[k - NB1] = (k - NB1) * CAP2;
}

// ---------------- level-1 partition (register-only, ballot-ranked coalesced writes) -----
__global__ __launch_bounds__(256) void k_part(
    const int* __restrict__ src, const int* __restrict__ dst,
    int* __restrict__ gcur, unsigned long long* __restrict__ part)
{
    __shared__ int bcnt[NB1];
    __shared__ int lcur[NB1];
    const int tid = threadIdx.x;
    const int ll  = tid & 63;
    const int base = blockIdx.x * PART_EPB;
    int sv[8], dv[8], bv[8];
    int mycnt[NB1] = {0, 0, 0, 0, 0, 0, 0, 0};
#pragma unroll
    for (int u = 0; u < 8; ++u) {
        int e = base + u * 256 + tid;
        bool val = e < N_EDGES;
        sv[u] = val ? src[e] : 0;
        dv[u] = val ? dst[e] : 0;
        bv[u] = val ? dv[u] / WIN1 : -1;
#pragma unroll
        for (int bk = 0; bk < NB1; ++bk) mycnt[bk] += (bv[u] == bk);
    }
    if (tid < NB1) bcnt[tid] = 0;
    __syncthreads();
#pragma unroll
    for (int bk = 0; bk < NB1; ++bk) {
        int c = mycnt[bk];
        for (int o = 1; o < 64; o <<= 1) c += __shfl_xor(c, o, 64);
        if (ll == 0 && c) atomicAdd(&bcnt[bk], c);
    }
    __syncthreads();
    if (tid < NB1) lcur[tid] = atomicAdd(&gcur[tid], bcnt[tid]);
    __syncthreads();
#pragma unroll
    for (int u = 0; u < 8; ++u) {
        unsigned long long masks[NB1]; int cnts[NB1];
#pragma unroll
        for (int bk = 0; bk < NB1; ++bk) {
            masks[bk] = __ballot(bv[u] == bk);
            cnts[bk]  = __popcll(masks[bk]);
        }
        int posv = 0;
        if (ll < NB1) posv = atomicAdd(&lcur[ll], cnts[ll]);
        int myoff = 0;
#pragma unroll
        for (int bk = 0; bk < NB1; ++bk) {
            int bb = __builtin_amdgcn_readlane(posv, bk);   // constant lane index
            if (bv[u] == bk) myoff = bb + __popcll(masks[bk] & ((1ULL << ll) - 1ULL));
        }
        if (bv[u] >= 0)
            part[myoff] = ((unsigned long long)(unsigned)dv[u] << 32) | (unsigned)sv[u];
    }
}

// ---------------- level-2 partition (LDS-atomic slots, no divergent readlane) ----------
__global__ __launch_bounds__(256) void k_part2(
    const unsigned long long* __restrict__ part, const int* __restrict__ gcur,
    int* __restrict__ gcur2, unsigned long long* __restrict__ part2)
{
    __shared__ int bcnt[SUBS];
    __shared__ int lcur[SUBS];
    const int w   = blockIdx.x & (NB1 - 1);
    const int g   = blockIdx.x >> 3;
    const int tid = threadIdx.x;
    const int b0  = w * CAP1;
    const int cnt = gcur[w] - b0;
    const int chunk = (cnt + 255) >> 8;
    const int lo = g * chunk;
    const int hi = min(lo + chunk, cnt);
    const int rounds = (hi > lo) ? ((hi - lo + 255) >> 8) : 0;   // <= 4
    const int nlo_base = w * WIN1;

    unsigned long long ev[4];
    int bkv[4];
    if (tid < SUBS) bcnt[tid] = 0;
    __syncthreads();
    for (int r = 0; r < rounds; ++r) {
        int i = lo + r * 256 + tid;
        bool val = i < hi;
        unsigned long long e = val ? part[b0 + i] : 0ULL;
        int bk = val ? ((int)(e >> 32) - nlo_base) / WIN2 : -1;
        ev[r] = e; bkv[r] = bk;
        if (val) atomicAdd(&bcnt[bk], 1);
    }
    __syncthreads();
    if (tid < SUBS) lcur[tid] = atomicAdd(&gcur2[w * SUBS + tid], bcnt[tid]);  // absolute base
    __syncthreads();
    for (int r = 0; r < rounds; ++r) {
        int mybk = bkv[r];
        if (mybk >= 0) {
            int off = atomicAdd(&lcur[mybk], 1);
            part2[off] = ev[r];
        }
    }
}

// ---------------- per-window LDS histogram -> deg ----------------
__global__ __launch_bounds__(512) void k_histw(
    const unsigned long long* __restrict__ part2, const int* __restrict__ gcur2,
    int* __restrict__ deg)
{
    __shared__ int cnt[WIN2];
    const int q = blockIdx.x;
    const int w = q >> 5, s = q & (SUBS - 1);
    const int nlo = w * WIN1 + s * WIN2;
    const int nhi = w * WIN1 + min((s + 1) * WIN2, WIN1);
    const int wn = nhi - nlo;
    for (int i = threadIdx.x; i < wn; i += 512) cnt[i] = 0;
    __syncthreads();
    const int b0 = q * CAP2;
    const int ec = gcur2[q] - b0;
    for (int i = threadIdx.x; i < ec; i += 512) {
        int d = (int)(part2[b0 + i] >> 32);
        atomicAdd(&cnt[d - nlo], 1);
    }
    __syncthreads();
    for (int i = threadIdx.x; i < wn; i += 512) deg[nlo + i] = cnt[i] + 1;  // +1 self-loop
}

// ---------------- window offsets: poff[q] = prefix of (ec_q + wn_q) — no deg sweep -----
__global__ void k_scan_off(const int* __restrict__ gcur2, int* __restrict__ poff) {
    __shared__ int wsum[4];
    const int q = threadIdx.x;            // 256 threads = 4 waves
    const int s = q & (SUBS - 1);
    const int wn = min((s + 1) * WIN2, WIN1) - s * WIN2;
    int v = (gcur2[q] - q * CAP2) + wn;   // window total degree (edges + self-loops)
    int lane = q & 63, wv = q >> 6;
    int sc = v;
    for (int o = 1; o < 64; o <<= 1) { int u = __shfl_up(sc, o, 64); if (lane >= o) sc += u; }
    if (lane == 63) wsum[wv] = sc;
    __syncthreads();
    int woff = 0;
    for (int i = 0; i < wv; ++i) woff += wsum[i];
    poff[q] = woff + sc - v;              // exclusive prefix
}

// ---------------- per-window: local scan -> row_ptr/dinv, then LDS-cursor sort ---------
__global__ __launch_bounds__(512) void k_sortw(
    const unsigned long long* __restrict__ part2, const int* __restrict__ gcur2,
    const int* __restrict__ poff, const int* __restrict__ deg,
    int* __restrict__ row_ptr, float* __restrict__ dinv, int* __restrict__ ssrc)
{
    __shared__ int cur[WIN2];
    __shared__ int wsum[8];
    const int q = blockIdx.x;
    const int w = q >> 5, s = q & (SUBS - 1);
    const int nlo = w * WIN1 + s * WIN2;
    const int nhi = w * WIN1 + min((s + 1) * WIN2, WIN1);
    const int wn = nhi - nlo;
    const int tid = threadIdx.x;          // 512 threads >= wn (391)

    // window-local exclusive scan of deg
    int v = (tid < wn) ? deg[nlo + tid] : 0;
    int lane = tid & 63, wv = tid >> 6;
    int sc = v;
    for (int o = 1; o < 64; o <<= 1) { int u = __shfl_up(sc, o, 64); if (lane >= o) sc += u; }
    if (lane == 63) wsum[wv] = sc;
    __syncthreads();
    int woff = 0;
    for (int i = 0; i < wv; ++i) woff += wsum[i];
    int rp = poff[q] + woff + sc - v;     // exclusive
    if (tid < wn) {
        row_ptr[nlo + tid] = rp;
        dinv[nlo + tid] = rsqrtf((float)v);
        cur[tid] = rp;
    }
    __syncthreads();

    // sort edges into exclusive ssrc region via LDS cursors
    const int b0 = q * CAP2;
    const int ec = gcur2[q] - b0;
    for (int i = tid; i < ec; i += 512) {
        unsigned long long e = part2[b0 + i];
        int d = (int)(e >> 32);
        int p = atomicAdd(&cur[d - nlo], 1);
        ssrc[p] = (int)(e & 0xffffffffu);
    }
}

// ---------------- dual GEMM: xp = relu(xb@pW + pb); tb = dinv .* (xb@W1) ----------------
__global__ __launch_bounds__(256) void k_gemm_dual(
    const unsigned short* __restrict__ xb, const unsigned short* __restrict__ pWt,
    const unsigned short* __restrict__ W1t, const float* __restrict__ pb,
    const float* __restrict__ dinv, unsigned short* __restrict__ xp,
    unsigned short* __restrict__ tb)
{
    const int tid  = threadIdx.x;
    const int wave = tid >> 6, lane = tid & 63;
    const int l15 = lane & 15, lg = lane >> 4;
    const int rbase = blockIdx.x * 64 + wave * 16;

    f32x4 accP[8], acc1[8];
#pragma unroll
    for (int i = 0; i < 8; ++i) { accP[i] = (f32x4)(0.0f); acc1[i] = (f32x4)(0.0f); }

    int arow = rbase + l15; if (arow >= N_NODES) arow = N_NODES - 1;

#pragma unroll
    for (int ks = 0; ks < 4; ++ks) {
        const int ko = ks * 32 + lg * 8;
        bf16x8 a = *(const bf16x8*)&xb[(size_t)arow * 128 + ko];
#pragma unroll
        for (int cf = 0; cf < 8; ++cf) {
            bf16x8 bP = *(const bf16x8*)&pWt[(size_t)(cf * 16 + l15) * 128 + ko];
            bf16x8 b1 = *(const bf16x8*)&W1t[(size_t)(cf * 16 + l15) * 128 + ko];
            accP[cf] = __builtin_amdgcn_mfma_f32_16x16x32_bf16(a, bP, accP[cf], 0, 0, 0);
            acc1[cf] = __builtin_amdgcn_mfma_f32_16x16x32_bf16(a, b1, acc1[cf], 0, 0, 0);
        }
    }
#pragma unroll
    for (int cf = 0; cf < 8; ++cf) {
        int col = cf * 16 + l15;
        float bv = pb[col];
#pragma unroll
        for (int j = 0; j < 4; ++j) {
            int row = rbase + lg * 4 + j;
            if (row < N_NODES) {
                float sc = dinv[row];
                xp[(size_t)row * 128 + col] = f2b(fmaxf(accP[cf][j] + bv, 0.0f));
                tb[(size_t)row * 128 + col] = f2b(acc1[cf][j] * sc);
            }
        }
    }
}

// ---------------- GEMM: out = dinv .* ( concat(A0..A_{NC-1}) @ W ) ----------------
template<int NC>
__global__ __launch_bounds__(256) void k_gemm(
    const unsigned short* __restrict__ A0, const unsigned short* __restrict__ A1,
    const unsigned short* __restrict__ A2, const unsigned short* __restrict__ WtG,
    const float* __restrict__ dinv, unsigned short* __restrict__ out)
{
    const int tid  = threadIdx.x;
    const int wave = tid >> 6, lane = tid & 63;
    const int l15 = lane & 15, lg = lane >> 4;
    const int K = NC * 128;
    const int rbase = blockIdx.x * 128 + wave * 32;

    f32x4 acc[2][8];
#pragma unroll
    for (int i = 0; i < 2; ++i)
#pragma unroll
        for (int j = 0; j < 8; ++j) acc[i][j] = (f32x4)(0.0f);

    int ar0 = rbase + l15;      if (ar0 >= N_NODES) ar0 = N_NODES - 1;
    int ar1 = rbase + 16 + l15; if (ar1 >= N_NODES) ar1 = N_NODES - 1;

    for (int c = 0; c < NC; ++c) {
        const unsigned short* Ac = (c == 0) ? A0 : ((c == 1) ? A1 : A2);
#pragma unroll
        for (int ks = 0; ks < 4; ++ks) {
            const int ko = ks * 32 + lg * 8;
            bf16x8 a0 = *(const bf16x8*)&Ac[(size_t)ar0 * 128 + ko];
            bf16x8 a1 = *(const bf16x8*)&Ac[(size_t)ar1 * 128 + ko];
#pragma unroll
            for (int cf = 0; cf < 8; ++cf) {
                bf16x8 b = *(const bf16x8*)&WtG[(size_t)(cf * 16 + l15) * K + c * 128 + ko];
                acc[0][cf] = __builtin_amdgcn_mfma_f32_16x16x32_bf16(a0, b, acc[0][cf], 0, 0, 0);
                acc[1][cf] = __builtin_amdgcn_mfma_f32_16x16x32_bf16(a1, b, acc[1][cf], 0, 0, 0);
            }
        }
    }
#pragma unroll
    for (int ai = 0; ai < 2; ++ai) {
#pragma unroll
        for (int j = 0; j < 4; ++j) {
            int row = rbase + ai * 16 + lg * 4 + j;
            if (row < N_NODES) {
                float sc = dinv[row];
#pragma unroll
                for (int cf = 0; cf < 8; ++cf)
                    out[(size_t)row * 128 + cf * 16 + l15] = f2b(acc[ai][cf][j] * sc);
            }
        }
    }
}

// ---------------- aggregation: out = relu(dinv_i * (sum t'_s + t'_i) + b) --------------
template<bool FINAL>
__global__ __launch_bounds__(256) void k_agg(
    const unsigned short* __restrict__ t, const int* __restrict__ ssrc,
    const int* __restrict__ row_ptr, const int* __restrict__ deg,
    const float* __restrict__ dinv, const float* __restrict__ bias,
    void* __restrict__ out_v)
{
    const int wave = threadIdx.x >> 6;
    const int lane = threadIdx.x & 63;
    const int node = blockIdx.x * 4 + wave;
    if (node >= N_NODES) return;

    const int beg = row_ptr[node];
    const int cnt = deg[node] - 1;
    float a0 = 0.0f, a1 = 0.0f;

    for (int kb = 0; kb < cnt; kb += 64) {
        const int rem = cnt - kb;
        const int lim = rem < 64 ? rem : 64;
        int sk = 0;
        if (lane < lim) sk = ssrc[beg + kb + lane];

        int k = 0;
        for (; k + 8 <= lim; k += 8) {
            unsigned int p[8];
#pragma unroll
            for (int u = 0; u < 8; ++u) {
                int s = __builtin_amdgcn_readlane(sk, k + u);   // wave-uniform lane
                p[u] = *(const unsigned int*)&t[(size_t)s * 128 + lane * 2];
            }
#pragma unroll
            for (int u = 0; u < 8; ++u) {
                a0 += b2f((unsigned short)(p[u] & 0xffffu));
                a1 += b2f((unsigned short)(p[u] >> 16));
            }
        }
        for (; k < lim; ++k) {
            int s0 = __builtin_amdgcn_readlane(sk, k);
            unsigned int p0 = *(const unsigned int*)&t[(size_t)s0 * 128 + lane * 2];
            a0 += b2f((unsigned short)(p0 & 0xffffu));
            a1 += b2f((unsigned short)(p0 >> 16));
        }
    }

    unsigned int ps = *(const unsigned int*)&t[(size_t)node * 128 + lane * 2];
    a0 += b2f((unsigned short)(ps & 0xffffu));
    a1 += b2f((unsigned short)(ps >> 16));

    float di = dinv[node];
    f32x2 bv = *(const f32x2*)&bias[lane * 2];
    float o0 = fmaxf(di * a0 + bv[0], 0.0f);
    float o1 = fmaxf(di * a1 + bv[1], 0.0f);
    if (FINAL) {
        f32x2 po; po[0] = o0; po[1] = o1;
        *(f32x2*)((float*)out_v + (size_t)node * 128 + lane * 2) = po;
    } else {
        unsigned short* out = (unsigned short*)out_v;
        unsigned int po = (unsigned int)f2b(o0) | ((unsigned int)f2b(o1) << 16);
        *(unsigned int*)&out[(size_t)node * 128 + lane * 2] = po;
    }
}

// ---------------- launch ----------------
extern "C" void kernel_launch(void* const* d_in, const int* in_sizes, int n_in,
                              void* d_out, int out_size, void* d_ws, size_t ws_size,
                              hipStream_t stream)
{
    const float* x  = (const float*)d_in[0];
    const int*   ei = (const int*)d_in[1];
    const float* pW = (const float*)d_in[2];
    const float* pb = (const float*)d_in[3];
    const float* W1 = (const float*)d_in[4];
    const float* b1 = (const float*)d_in[5];
    const float* W2 = (const float*)d_in[6];
    const float* b2 = (const float*)d_in[7];
    const float* W3 = (const float*)d_in[8];
    const float* b3 = (const float*)d_in[9];
    const int* src = ei;
    const int* dst = ei + N_EDGES;

    char* ws = (char*)d_ws;
    size_t off = 0;
    auto alloc = [&](size_t bytes) -> char* {
        char* p = ws + off; off += (bytes + 255) & ~(size_t)255; return p;
    };
    const size_t NB = (size_t)N_NODES * 128;
    unsigned short* xb = (unsigned short*)alloc(NB * 2);
    unsigned short* xp = (unsigned short*)alloc(NB * 2);
    unsigned short* h1 = (unsigned short*)alloc(NB * 2);
    unsigned short* h2 = (unsigned short*)alloc(NB * 2);   // part2 (16.8 MB) aliases here
    unsigned short* tb = (unsigned short*)alloc(NB * 2);   // part  (13.1 MB) aliases here
    unsigned short* Wb = (unsigned short*)alloc((size_t)NWEL * 2);
    int*   deg  = (int*)alloc((size_t)N_NODES * 4);
    int*   rp   = (int*)alloc((size_t)N_NODES * 4);
    float* dinv = (float*)alloc((size_t)N_NODES * 4);
    int*   poff = (int*)alloc((size_t)NWIN * 4);
    int*   gcur = (int*)alloc((size_t)NB1 * 4);
    int*   gcur2= (int*)alloc((size_t)NWIN * 4);
    int*   ssrc = (int*)alloc((size_t)(N_EDGES + N_NODES) * 4);

    unsigned long long* part  = (unsigned long long*)tb;   // dead before gemm_dual writes tb
    unsigned long long* part2 = (unsigned long long*)h2;   // dead before agg2 writes h2

    unsigned short* pWt = Wb;
    unsigned short* W1t = Wb + 16384;
    unsigned short* W2t = Wb + 32768;
    unsigned short* W3t = Wb + 65536;

    const int prep_blocks = (NQX + NWEL + NB1 + NWIN + 255) / 256;
    k_prep<<<prep_blocks, 256, 0, stream>>>(x, pW, W1, W2, W3, xb, Wb, gcur, gcur2);
    k_part<<<PART_BLOCKS, 256, 0, stream>>>(src, dst, gcur, part);
    k_part2<<<PART2_BLOCKS, 256, 0, stream>>>(part, gcur, gcur2, part2);
    k_histw<<<NWIN, 512, 0, stream>>>(part2, gcur2, deg);
    k_scan_off<<<1, 256, 0, stream>>>(gcur2, poff);
    k_sortw<<<NWIN, 512, 0, stream>>>(part2, gcur2, poff, deg, rp, dinv, ssrc);

    const int dblocks = (N_NODES + 63) / 64;
    const int gblocks = (N_NODES + 127) / 128;
    const int ablocks = (N_NODES + 3) / 4;

    k_gemm_dual<<<dblocks, 256, 0, stream>>>(xb, pWt, W1t, pb, dinv, xp, tb);
    k_agg<false><<<ablocks, 256, 0, stream>>>(tb, ssrc, rp, deg, dinv, b1, h1);
    k_gemm<2><<<gblocks, 256, 0, stream>>>(xp, h1, nullptr, W2t, dinv, tb);
    k_agg<false><<<ablocks, 256, 0, stream>>>(tb, ssrc, rp, deg, dinv, b2, h2);
    k_gemm<3><<<gblocks, 256, 0, stream>>>(xp, h1, h2, W3t, dinv, tb);
    k_agg<true><<<ablocks, 256, 0, stream>>>(tb, ssrc, rp, deg, dinv, b3, d_out);
}